// Round 4
// baseline (591.257 us; speedup 1.0000x reference)
//
#include <hip/hip_runtime.h>

// SALSA3D: C=64, Ci=16, D=8, H=W=160, K=3, S=2, P=1 -> nH=nW=80, L=6400, F=144
// proj -> unfold(bf16 Q/K row-major, V^T f-major) -> MFMA flash attn (S^T=K@Q^T,
// ksplit=10/5/4, bf16 partials) -> merge -> fold/norm -> final add
//
// R4 (attn occupancy): Pl overlays Ks (disjoint live ranges; +1 barrier/iter),
// odd-dword-stride pads (Ks 146, Vs 66, Pl 66 -> conflict-FREE), LDS 63744 ->
// 39808 B -> 4 blocks/CU (16 waves/CU, 2x occupancy), launch_bounds(256,4),
// ksplit->10 (1000 blocks, all-resident) gated on ws>=48.9MB. Merge widened.
//
// ws layout (float offsets), lifetime overlays (ns = ksplit):
//   PatQK bf16 [2][2][6400][144]         f[0 .. 1,843,200)          dead after attn
//   VT    bf16 [2][144][6400]            f[1,843,200 .. 2,764,800)  dead after attn
//   ml    f32  [2][ns][6400]x2           f[2,764,800 .. +25,600*ns... wait 2*ns*6400*2)
//   P3    f32  [2][3][16][25600]         f[off_P3 .. +2,457,600)    dead after unfold
//   Opart bf16 [2][ns][6400][144]        overlays P3
//   Zi    f32  [2][6400][144]            overlays PatQK
//   zi2   f32  [2][16][25600]            overlays VT
// high-water: ns=10: 48.9 MB; ns=5: 30.0 MB; ns=4: 26.2 MB (gated on ws_size)

#define NPIX 25600
#define LOG2E10 14.42695040888963f  // 10 * log2(e): softmax_scale folded into exp2
#define TAU 0.75f                   // defer-max threshold (score units)

#define KS_LD 146   // Ks row stride (shorts): 73 dwords, odd -> conflict-free
#define VS_LD 66    // Vs row stride: 33 dwords, odd -> conflict-free
#define PL_LD 66    // Pl row stride: 33 dwords, odd -> conflict-free
#define KS_SH (64 * KS_LD)          // 9344 shorts (Pl overlay: 4*32*66=8448 <= this)
#define VS_SH (160 * VS_LD)         // 10560 shorts (rows 144..159 zeroed, read-only)

typedef float floatx16 __attribute__((ext_vector_type(16)));
typedef short short8 __attribute__((ext_vector_type(8)));

__device__ inline unsigned short f2bf(float x) {
    union { float f; unsigned int u; } v; v.f = x;
    unsigned int r = v.u + 0x7fffu + ((v.u >> 16) & 1u);
    return (unsigned short)(r >> 16);
}
__device__ inline float bf2f(unsigned short u) {
    union { unsigned int u; float f; } v; v.u = ((unsigned int)u) << 16;
    return v.f;
}

// ---------------- K1: 1x1x1 conv projections at mid depth ----------------
// c-split x4 + LDS tree reduce (R2 version, ~53us win vs R0 structure).
__global__ __launch_bounds__(256) void k_proj(
    const float* __restrict__ b,
    const float* __restrict__ gw, const float* __restrict__ gb,
    const float* __restrict__ thw, const float* __restrict__ thb,
    const float* __restrict__ phw, const float* __restrict__ phb,
    float* __restrict__ P3) {
    __shared__ float Wt[3 * 64 * 16];   // [s][c][o16] transposed
    __shared__ float Bl[48];
    __shared__ float red[2][48][64];
    int tid = threadIdx.x;
    int g = blockIdx.y;
    int px = tid & 63;
    int cq = tid >> 6;
    int pix = blockIdx.x * 64 + px;

    for (int i = tid; i < 1024; i += 256) {
        int o = i & 15, c = i >> 4;
        Wt[(0 * 64 + c) * 16 + o] = gw[o * 64 + c];   // s=0: query (g_w)
        Wt[(1 * 64 + c) * 16 + o] = phw[o * 64 + c];  // s=1: key   (phi_w)
        Wt[(2 * 64 + c) * 16 + o] = thw[o * 64 + c];  // s=2: value (theta_w)
    }
    if (tid < 16) { Bl[tid] = gb[tid]; Bl[16 + tid] = phb[tid]; Bl[32 + tid] = thb[tid]; }
    __syncthreads();

    float acc[48];
#pragma unroll
    for (int o = 0; o < 48; o++) acc[o] = 0.f;
    const float* bp = b + (size_t)g * 64 * 8 * NPIX + (size_t)4 * NPIX + pix;
#pragma unroll
    for (int i = 0; i < 16; i++) {
        int c = cq * 16 + i;
        float xv = bp[(size_t)c * 8 * NPIX];
#pragma unroll
        for (int s = 0; s < 3; s++) {
            const float* wp = &Wt[(s * 64 + c) * 16];  // wave-uniform: LDS broadcast
#pragma unroll
            for (int o = 0; o < 16; o++)
                acc[s * 16 + o] += wp[o] * xv;
        }
    }
    if (cq >= 2) {
#pragma unroll
        for (int o = 0; o < 48; o++) red[cq - 2][o][px] = acc[o];
    }
    __syncthreads();
    if (cq < 2) {
#pragma unroll
        for (int o = 0; o < 48; o++) acc[o] += red[cq][o][px];
    }
    __syncthreads();
    if (cq == 1) {
#pragma unroll
        for (int o = 0; o < 48; o++) red[0][o][px] = acc[o];
    }
    __syncthreads();
    if (cq == 0) {
#pragma unroll
        for (int o = 0; o < 48; o++)
            P3[(size_t)(g * 48 + o) * NPIX + pix] = acc[o] + red[0][o][px] + Bl[o];
    }
}

// ---------------- K2a: unfold Q,K -> bf16 [g][s][l][144] ----------------
__global__ void k_unfold_qk(const float* __restrict__ P3, unsigned short* __restrict__ Pat) {
    int idx = blockIdx.x * 256 + threadIdx.x;  // 2*2*6400*144 exact
    int f = idx % 144;
    int l = (idx / 144) % 6400;
    int s = (idx / (144 * 6400)) & 1;
    int g = idx / (2 * 144 * 6400);
    int ci = f / 9, kr = (f % 9) / 3, kc = f % 3;
    int oh = l / 80, ow = l % 80;
    int h = oh * 2 + kr - 1, w = ow * 2 + kc - 1;
    float v = 0.f;
    if (h >= 0 && h < 160 && w >= 0 && w < 160)
        v = P3[(size_t)(g * 48 + s * 16 + ci) * NPIX + h * 160 + w];
    Pat[idx] = f2bf(v);
}

// ---------------- K2b: unfold V transposed -> bf16 [g][144][6400] ----------------
__global__ void k_unfold_v(const float* __restrict__ P3, unsigned short* __restrict__ VT) {
    int idx = blockIdx.x * 256 + threadIdx.x;  // 2*144*6400 exact
    int l = idx % 6400;
    int f = (idx / 6400) % 144;
    int g = idx / (144 * 6400);
    int ci = f / 9, kr = (f % 9) / 3, kc = f % 3;
    int oh = l / 80, ow = l % 80;
    int h = oh * 2 + kr - 1, w = ow * 2 + kc - 1;
    float v = 0.f;
    if (h >= 0 && h < 160 && w >= 0 && w < 160)
        v = P3[(size_t)(g * 48 + 32 + ci) * NPIX + h * 160 + w];
    VT[idx] = f2bf(v);
}

// ---------------- K3: MFMA flash attention (S^T = K@Q^T) ----------------
// 256 thr = 4 waves x 32 queries, keys in nsplit ranges of kps, tiles of 64.
// 3-barrier iter: [A] stage visible -> issue next loads -> S^T (Ks) -> softmax
// -> [B] all Ks reads done -> write Pl (OVERLAYS Ks) -> PV (Pl+Vs) -> [C] ->
// staging writes. LDS 39808 B -> 4 blocks/CU.
__global__ __launch_bounds__(256, 4) void k_attn(
    const unsigned short* __restrict__ PatQK, const unsigned short* __restrict__ VT,
    float* __restrict__ ml, unsigned short* __restrict__ Opart,
    int nsplit, int kps) {
    __shared__ unsigned short SM[KS_SH + VS_SH];  // 19904 shorts = 39808 B
    unsigned short* Ks = SM;
    unsigned short* Vs = SM + KS_SH;
    unsigned short* Pl = SM;                      // overlays Ks (disjoint live range)

    int tid = threadIdx.x;
    int lane = tid & 63;
    int w = tid >> 6;
    int l31 = lane & 31;
    int h5 = lane >> 5;
    int split = blockIdx.y, g = blockIdx.z;
    int q = blockIdx.x * 128 + w * 32 + l31;
    int nIter = kps >> 6;

    const unsigned short* Qg = PatQK + ((size_t)g * 2 + 0) * 6400 * 144;
    const unsigned short* Kg = PatQK + ((size_t)g * 2 + 1) * 6400 * 144 + (size_t)split * kps * 144;
    const unsigned short* Vg = VT + (size_t)g * 144 * 6400 + split * kps;

    // Q fragments (B operand) pinned in registers
    short8 qf[9];
#pragma unroll
    for (int fs = 0; fs < 9; fs++)
        qf[fs] = *(const short8*)(Qg + (size_t)q * 144 + fs * 16 + h5 * 8);

    floatx16 O[5];
#pragma unroll
    for (int i = 0; i < 5; i++) O[i] = (floatx16)0.f;
    float m = -1e30f, lsum = 0.f;

    unsigned short* Plw = Pl + w * (32 * PL_LD);

    // zero Vs pad rows 144..159 (read by PV ft=4; outputs f>=144 discarded, but
    // keep them clean): 16*VS_LD shorts
    for (int i = tid; i < 16 * VS_LD; i += 256) Vs[144 * VS_LD + i] = 0;

    short8 stg[9];
    // prologue: stage tile 0
    {
#pragma unroll
        for (int j = 0; j < 9; j++) {
            int c = tid + 256 * j;
            if (c < 1152) {
                int row = c / 18, col = c - row * 18;
                stg[j] = *(const short8*)(Kg + row * 144 + col * 8);
            } else {
                int vv = c - 1152;
                int f = vv >> 3, col = vv & 7;
                stg[j] = *(const short8*)(Vg + (size_t)f * 6400 + col * 8);
            }
        }
#pragma unroll
        for (int j = 0; j < 9; j++) {
            int c = tid + 256 * j;
            if (c < 1152) {
                int row = c / 18, col = c - row * 18;
                *(short8*)&Ks[row * KS_LD + col * 8] = stg[j];
            } else {
                int vv = c - 1152;
                int f = vv >> 3, col = vv & 7;
                *(short8*)&Vs[f * VS_LD + col * 8] = stg[j];
            }
        }
    }

    for (int it = 0; it < nIter; it++) {
        __syncthreads();  // [A] staged tile `it` visible

        // issue next tile's global loads early; latency hides under compute
        if (it + 1 < nIter) {
            const unsigned short* Kt = Kg + (it + 1) * 64 * 144;
            const unsigned short* Vt = Vg + (it + 1) * 64;
#pragma unroll
            for (int j = 0; j < 9; j++) {
                int c = tid + 256 * j;
                if (c < 1152) {
                    int row = c / 18, col = c - row * 18;
                    stg[j] = *(const short8*)(Kt + row * 144 + col * 8);
                } else {
                    int vv = c - 1152;
                    int f = vv >> 3, col = vv & 7;
                    stg[j] = *(const short8*)(Vt + (size_t)f * 6400 + col * 8);
                }
            }
        }

        // S^T: two 32x32 C-tiles (keys 0-31 / 32-63), reduce over f=144 in 9 steps
        floatx16 S0 = (floatx16)0.f, S1 = (floatx16)0.f;
#pragma unroll
        for (int fs = 0; fs < 9; fs++) {
            short8 a0 = *(const short8*)&Ks[l31 * KS_LD + fs * 16 + h5 * 8];
            short8 a1 = *(const short8*)&Ks[(32 + l31) * KS_LD + fs * 16 + h5 * 8];
            S0 = __builtin_amdgcn_mfma_f32_32x32x16_bf16(a0, qf[fs], S0, 0, 0, 0);
            S1 = __builtin_amdgcn_mfma_f32_32x32x16_bf16(a1, qf[fs], S1, 0, 0, 0);
        }

        // online softmax: this lane's 32 scores all belong to query col=l31
        float mt = -1e30f;
#pragma unroll
        for (int r = 0; r < 16; r++) { mt = fmaxf(mt, S0[r]); mt = fmaxf(mt, S1[r]); }
        mt = fmaxf(mt, __shfl_xor(mt, 32, 64));
        bool upd = mt > m + TAU;  // defer-max: P bounded by 2^(14.43*TAU)
        float mnew = upd ? mt : m;
        float alpha = upd ? exp2f(LOG2E10 * (m - mnew)) : 1.f;
        float ps = 0.f;
#pragma unroll
        for (int r = 0; r < 16; r++) {  // exp in place: S reused as P
            S0[r] = exp2f(LOG2E10 * (S0[r] - mnew));
            S1[r] = exp2f(LOG2E10 * (S1[r] - mnew));
            ps += S0[r] + S1[r];
        }
        ps += __shfl_xor(ps, 32, 64);
        lsum = lsum * alpha + ps;
        m = mnew;
        if (__any(alpha < 1.f)) {
#pragma unroll
            for (int t5 = 0; t5 < 5; t5++)
#pragma unroll
                for (int r = 0; r < 16; r++) O[t5][r] *= alpha;
        }

        __syncthreads();  // [B] all waves done reading Ks -> Pl overlay is safe

        // P^T -> per-wave LDS as [q][k] bf16 (k = 8*rg + 4*h5 + rr, +32 tile1)
#pragma unroll
        for (int rg = 0; rg < 4; rg++) {
            ushort4 w0, w1;
            w0.x = f2bf(S0[4 * rg + 0]); w0.y = f2bf(S0[4 * rg + 1]);
            w0.z = f2bf(S0[4 * rg + 2]); w0.w = f2bf(S0[4 * rg + 3]);
            w1.x = f2bf(S1[4 * rg + 0]); w1.y = f2bf(S1[4 * rg + 1]);
            w1.z = f2bf(S1[4 * rg + 2]); w1.w = f2bf(S1[4 * rg + 3]);
            *(ushort4*)&Plw[l31 * PL_LD + rg * 8 + h5 * 4] = w0;
            *(ushort4*)&Plw[l31 * PL_LD + 32 + rg * 8 + h5 * 4] = w1;
        }

        // O^T += V^T @ P^T  (A from Vs, B from own-wave Plw)
#pragma unroll
        for (int ks = 0; ks < 4; ks++) {
            short8 pb = *(const short8*)&Plw[l31 * PL_LD + ks * 16 + h5 * 8];
#pragma unroll
            for (int ft = 0; ft < 5; ft++) {
                short8 va = *(const short8*)&Vs[(ft * 32 + l31) * VS_LD + ks * 16 + h5 * 8];
                O[ft] = __builtin_amdgcn_mfma_f32_32x32x16_bf16(va, pb, O[ft], 0, 0, 0);
            }
        }

        if (it + 1 < nIter) {
            __syncthreads();  // [C] PV done: Pl dead, Ks/Vs writable
#pragma unroll
            for (int j = 0; j < 9; j++) {
                int c = tid + 256 * j;
                if (c < 1152) {
                    int row = c / 18, col = c - row * 18;
                    *(short8*)&Ks[row * KS_LD + col * 8] = stg[j];
                } else {
                    int vv = c - 1152;
                    int f = vv >> 3, col = vv & 7;
                    *(short8*)&Vs[f * VS_LD + col * 8] = stg[j];
                }
            }
        }
    }

    if (h5 == 0)
        ((float2*)ml)[((size_t)g * nsplit + split) * 6400 + q] = make_float2(m, lsum);

    unsigned short* Og = Opart + (((size_t)g * nsplit + split) * 6400 + q) * 144;
#pragma unroll
    for (int ft = 0; ft < 5; ft++)
#pragma unroll
        for (int rg = 0; rg < 4; rg++) {
            int f = ft * 32 + rg * 8 + h5 * 4;
            if (f < 144) {
                ushort4 st;
                st.x = f2bf(O[ft][4 * rg + 0]); st.y = f2bf(O[ft][4 * rg + 1]);
                st.z = f2bf(O[ft][4 * rg + 2]); st.w = f2bf(O[ft][4 * rg + 3]);
                *(ushort4*)(Og + f) = st;
            }
        }
}

// ---------------- K3b: merge ksplit partials (up to 10) ----------------
__global__ void k_merge(const float* __restrict__ mlp, const unsigned short* __restrict__ Opart,
                        float* __restrict__ Zi, int nsplit) {
    int idx = blockIdx.x * 256 + threadIdx.x;  // 2*6400*36 exact
    int fg = idx % 36;
    int q = (idx / 36) % 6400;
    int g = idx / (36 * 6400);
    const float2* ml2 = (const float2*)mlp;
    float2 s[10];
    float ms = -1e30f;
#pragma unroll
    for (int k = 0; k < 10; k++) {
        s[k] = (k < nsplit) ? ml2[((size_t)g * nsplit + k) * 6400 + q]
                            : make_float2(-1e30f, 0.f);
        ms = fmaxf(ms, s[k].x);
    }
    float wgt[10], denom = 0.f;
#pragma unroll
    for (int k = 0; k < 10; k++) {
        wgt[k] = exp2f(LOG2E10 * (s[k].x - ms));  // sentinel -> 0
        denom += wgt[k] * s[k].y;
    }
    float inv = 1.f / denom;
    float a0 = 0.f, a1 = 0.f, a2 = 0.f, a3 = 0.f;
#pragma unroll
    for (int k = 0; k < 10; k++) {
        if (k < nsplit) {
            ushort4 u = *(const ushort4*)(Opart + (((size_t)g * nsplit + k) * 6400 + q) * 144 + fg * 4);
            a0 += wgt[k] * bf2f(u.x); a1 += wgt[k] * bf2f(u.y);
            a2 += wgt[k] * bf2f(u.z); a3 += wgt[k] * bf2f(u.w);
        }
    }
    float4 out = make_float4(a0 * inv, a1 * inv, a2 * inv, a3 * inv);
    *(float4*)(Zi + ((size_t)g * 6400 + q) * 144 + fg * 4) = out;
}

// ---------------- K4: fold (overlap-add) + mask normalization ----------------
__global__ void k_fold(const float* __restrict__ Zi, float* __restrict__ zi2) {
    int idx = blockIdx.x * 256 + threadIdx.x;  // 2*16*25600 exact
    int pix = idx % NPIX;
    int ci = (idx / NPIX) & 15;
    int g = idx / (16 * NPIX);
    int h = pix / 160, w = pix % 160;
    int ohs[2], krs[2], nh = 0;
#pragma unroll
    for (int kr = 0; kr < 3; kr++) {
        int t = h + 1 - kr;
        if (t >= 0 && (t & 1) == 0 && (t >> 1) < 80) { ohs[nh] = t >> 1; krs[nh] = kr; nh++; }
    }
    int ows[2], kcs[2], nw = 0;
#pragma unroll
    for (int kc = 0; kc < 3; kc++) {
        int t = w + 1 - kc;
        if (t >= 0 && (t & 1) == 0 && (t >> 1) < 80) { ows[nw] = t >> 1; kcs[nw] = kc; nw++; }
    }
    float sm = 0.f;
    for (int a = 0; a < nh; a++)
        for (int bb = 0; bb < nw; bb++) {
            int l = ohs[a] * 80 + ows[bb];
            int f = ci * 9 + krs[a] * 3 + kcs[bb];
            sm += Zi[((size_t)g * 6400 + l) * 144 + f];
        }
    zi2[idx] = sm / (float)(nh * nw);
}

// ---------------- K5: out = b + conv1x1(zi2 broadcast over D) ----------------
__global__ void k_final(const float* __restrict__ b, const float* __restrict__ zi2,
                        const float* __restrict__ Ww, const float* __restrict__ Wb,
                        float* __restrict__ out) {
    __shared__ float z[16 * 64];
    __shared__ float Wl[64 * 16];
    __shared__ float Bl[64];
    int tid = threadIdx.x;
    int g = blockIdx.y;
    int pxb = blockIdx.x * 64;
    for (int i = tid; i < 1024; i += 256) {
        int ci = i >> 6, px = i & 63;
        z[i] = zi2[(size_t)(g * 16 + ci) * NPIX + pxb + px];
        Wl[i] = Ww[i];
    }
    if (tid < 64) Bl[tid] = Wb[tid];
    __syncthreads();

    int px4 = tid & 15;
    int cg = tid >> 4;
    float acc[4][4];
#pragma unroll
    for (int c4 = 0; c4 < 4; c4++) {
        float bv = Bl[cg + 16 * c4];
#pragma unroll
        for (int j = 0; j < 4; j++) acc[c4][j] = bv;
    }
#pragma unroll
    for (int ci = 0; ci < 16; ci++) {
        float zv[4];
#pragma unroll
        for (int j = 0; j < 4; j++) zv[j] = z[ci * 64 + px4 * 4 + j];
#pragma unroll
        for (int c4 = 0; c4 < 4; c4++) {
            float wv = Wl[(cg + 16 * c4) * 16 + ci];
#pragma unroll
            for (int j = 0; j < 4; j++) acc[c4][j] += wv * zv[j];
        }
    }
    for (int d = 0; d < 8; d++) {
#pragma unroll
        for (int c4 = 0; c4 < 4; c4++) {
            int c = cg + 16 * c4;
            size_t base = ((size_t)(g * 64 + c) * 8 + d) * NPIX + pxb + px4 * 4;
            float4 bv = *(const float4*)(b + base);
            float4 ov = make_float4(bv.x + acc[c4][0], bv.y + acc[c4][1],
                                    bv.z + acc[c4][2], bv.w + acc[c4][3]);
            *(float4*)(out + base) = ov;
        }
    }
}

extern "C" void kernel_launch(void* const* d_in, const int* in_sizes, int n_in,
                              void* d_out, int out_size, void* d_ws, size_t ws_size,
                              hipStream_t stream) {
    const float* b   = (const float*)d_in[0];
    const float* gw  = (const float*)d_in[1];
    const float* gb  = (const float*)d_in[2];
    const float* thw = (const float*)d_in[3];
    const float* thb = (const float*)d_in[4];
    const float* phw = (const float*)d_in[5];
    const float* phb = (const float*)d_in[6];
    const float* Ww  = (const float*)d_in[7];
    const float* Wb  = (const float*)d_in[8];
    float* out = (float*)d_out;
    float* ws = (float*)d_ws;

    // ns=10: 1000 blocks, all-resident at 4 blocks/CU. Gated on ws size.
    // high-water(ns) bytes = (2764800 + 2*ns*6400*2 + max(2457600, ns*6400*144)) * 4
    const size_t need10 = 48947200;
    const size_t need5  = 30003200;
    int ns = (ws_size >= need10) ? 10 : (ws_size >= need5) ? 5 : 4;
    int kps = 6400 / ns;  // 640 / 1280 / 1600 -- all multiples of 64

    unsigned short* PatQK = (unsigned short*)ws;                       // 3,686,400 bf16
    unsigned short* VT    = (unsigned short*)(ws + 1843200);           // 1,843,200 bf16
    float*          ml    = ws + 2764800;                              // 2*ns*6400*2 f32
    size_t off_P3 = 2764800 + (size_t)2 * ns * 6400 * 2;
    float*          P3    = ws + off_P3;                               // 2,457,600 f32
    unsigned short* Opart = (unsigned short*)(ws + off_P3);            // overlays P3
    float*          Zi    = ws;                                        // overlays PatQK
    float*          zi2   = ws + 1843200;                              // overlays VT

    k_proj<<<dim3(400, 2), 256, 0, stream>>>(b, gw, gb, thw, thb, phw, phb, P3);
    k_unfold_qk<<<dim3(14400), 256, 0, stream>>>(P3, PatQK);
    k_unfold_v<<<dim3(7200), 256, 0, stream>>>(P3, VT);
    k_attn<<<dim3(50, ns, 2), 256, 0, stream>>>(PatQK, VT, ml, Opart, ns, kps);
    k_merge<<<dim3(1800), 256, 0, stream>>>(ml, Opart, Zi, ns);
    k_fold<<<dim3(3200), 256, 0, stream>>>(Zi, zi2);
    k_final<<<dim3(400, 2), 256, 0, stream>>>(b, zi2, Ww, Wb, out);
}

// Round 6
// 338.600 us; speedup vs baseline: 1.7462x; 1.7462x over previous
//
#include <hip/hip_runtime.h>

// SALSA3D: C=64, Ci=16, D=8, H=W=160, K=3, S=2, P=1 -> nH=nW=80, L=6400, F=144
// proj -> unfold(bf16 Q/K row-major, V^T f-major) -> MFMA flash attn (S^T=K@Q^T,
// ksplit=5or4, bf16 partials) -> merge -> fold/norm -> final add
//
// R6 = R5 resubmitted verbatim (R5 bench was an infra failure, no data):
//  - k_attn: exact R3 revert (97us known-good). R4's launch_bounds(256,4)
//    forced VGPR 128->64 and spilled O[5]+qf+stg to scratch (FETCH 36->644MB).
//    Lesson: attn occupancy is REGISTER-limited (O[5]=80 regs/wave) -> 2
//    blocks/CU is structural; LDS shrink alone gains nothing.
//  - k_unfold_qk/v: thread-per-8-outputs, single aligned short8 (16B) store
//    (was: per-element scalar 2B stores at 288B inter-lane stride, ~3% write
//    coalescing). Address ALU amortized 8x.
//
// ws layout (float offsets), lifetime overlays (ns = ksplit):
//   PatQK bf16 [2][2][6400][144]         f[0 .. 1,843,200)          dead after attn
//   VT    bf16 [2][144][6400]            f[1,843,200 .. 2,764,800)  dead after attn
//   ml    f32  [2][ns][6400]x2           f[2,764,800 .. +2*ns*6400*2)
//   P3    f32  [2][3][16][25600]         f[off_P3 .. +2,457,600)    dead after unfold
//   Opart bf16 [2][ns][6400][144]        overlays P3
//   Zi    f32  [2][6400][144]            overlays PatQK
//   zi2   f32  [2][16][25600]            overlays VT
// high-water ns=5: 30.0 MB; ns=4: 26.2 MB (gated on ws_size)

#define NPIX 25600
#define LOG2E10 14.42695040888963f  // 10 * log2(e): softmax_scale folded into exp2
#define TAU 0.75f                   // defer-max threshold (score units)

typedef float floatx16 __attribute__((ext_vector_type(16)));
typedef short short8 __attribute__((ext_vector_type(8)));

__device__ inline unsigned short f2bf(float x) {
    union { float f; unsigned int u; } v; v.f = x;
    unsigned int r = v.u + 0x7fffu + ((v.u >> 16) & 1u);
    return (unsigned short)(r >> 16);
}
__device__ inline float bf2f(unsigned short u) {
    union { unsigned int u; float f; } v; v.u = ((unsigned int)u) << 16;
    return v.f;
}

// ---------------- K1: 1x1x1 conv projections at mid depth ----------------
// c-split x4 + LDS tree reduce (R2 version, ~53us win vs R0 structure).
__global__ __launch_bounds__(256) void k_proj(
    const float* __restrict__ b,
    const float* __restrict__ gw, const float* __restrict__ gb,
    const float* __restrict__ thw, const float* __restrict__ thb,
    const float* __restrict__ phw, const float* __restrict__ phb,
    float* __restrict__ P3) {
    __shared__ float Wt[3 * 64 * 16];   // [s][c][o16] transposed
    __shared__ float Bl[48];
    __shared__ float red[2][48][64];
    int tid = threadIdx.x;
    int g = blockIdx.y;
    int px = tid & 63;
    int cq = tid >> 6;
    int pix = blockIdx.x * 64 + px;

    for (int i = tid; i < 1024; i += 256) {
        int o = i & 15, c = i >> 4;
        Wt[(0 * 64 + c) * 16 + o] = gw[o * 64 + c];   // s=0: query (g_w)
        Wt[(1 * 64 + c) * 16 + o] = phw[o * 64 + c];  // s=1: key   (phi_w)
        Wt[(2 * 64 + c) * 16 + o] = thw[o * 64 + c];  // s=2: value (theta_w)
    }
    if (tid < 16) { Bl[tid] = gb[tid]; Bl[16 + tid] = phb[tid]; Bl[32 + tid] = thb[tid]; }
    __syncthreads();

    float acc[48];
#pragma unroll
    for (int o = 0; o < 48; o++) acc[o] = 0.f;
    const float* bp = b + (size_t)g * 64 * 8 * NPIX + (size_t)4 * NPIX + pix;
#pragma unroll
    for (int i = 0; i < 16; i++) {
        int c = cq * 16 + i;
        float xv = bp[(size_t)c * 8 * NPIX];
#pragma unroll
        for (int s = 0; s < 3; s++) {
            const float* wp = &Wt[(s * 64 + c) * 16];  // wave-uniform: LDS broadcast
#pragma unroll
            for (int o = 0; o < 16; o++)
                acc[s * 16 + o] += wp[o] * xv;
        }
    }
    if (cq >= 2) {
#pragma unroll
        for (int o = 0; o < 48; o++) red[cq - 2][o][px] = acc[o];
    }
    __syncthreads();
    if (cq < 2) {
#pragma unroll
        for (int o = 0; o < 48; o++) acc[o] += red[cq][o][px];
    }
    __syncthreads();
    if (cq == 1) {
#pragma unroll
        for (int o = 0; o < 48; o++) red[0][o][px] = acc[o];
    }
    __syncthreads();
    if (cq == 0) {
#pragma unroll
        for (int o = 0; o < 48; o++)
            P3[(size_t)(g * 48 + o) * NPIX + pix] = acc[o] + red[0][o][px] + Bl[o];
    }
}

// ---------------- K2a: unfold Q,K -> bf16 [g][s][l][144] ----------------
// thread per (g,s,l,f-octet): 8 outputs, one aligned 16B short8 store.
__global__ void k_unfold_qk(const float* __restrict__ P3, unsigned short* __restrict__ Pat) {
    int idx = blockIdx.x * 256 + threadIdx.x;  // 2*2*6400*18 = 460,800 exact
    int j = idx % 18;
    int rest = idx / 18;
    int l = rest % 6400;
    int gs = rest / 6400;          // 0..3
    int s = gs & 1, g = gs >> 1;
    int oh = l / 80, ow = l % 80;
    int h0 = oh * 2 - 1, w0 = ow * 2 - 1;
    const float* src = P3 + (size_t)(g * 48 + s * 16) * NPIX;
    short8 outv;
#pragma unroll
    for (int e = 0; e < 8; e++) {
        int f = j * 8 + e;
        int ci = f / 9;
        int rem = f - ci * 9;
        int kr = rem / 3;
        int kc = rem - kr * 3;
        int h = h0 + kr, w = w0 + kc;
        float v = 0.f;
        if (h >= 0 && h < 160 && w >= 0 && w < 160)
            v = src[(size_t)ci * NPIX + h * 160 + w];
        outv[e] = (short)f2bf(v);
    }
    *(short8*)(Pat + ((size_t)gs * 6400 + l) * 144 + j * 8) = outv;
}

// ---------------- K2b: unfold V transposed -> bf16 [g][144][6400] ----------------
// thread per (g,f,l-octet): 8 consecutive l (same oh, same f), one 16B store.
__global__ void k_unfold_v(const float* __restrict__ P3, unsigned short* __restrict__ VT) {
    int idx = blockIdx.x * 256 + threadIdx.x;  // 2*144*800 = 230,400 exact
    int lc = idx % 800;
    int f = (idx / 800) % 144;
    int g = idx / (800 * 144);
    int l0 = lc * 8;
    int oh = l0 / 80, ow0 = l0 - oh * 80;      // l0 multiple of 8, 80%8==0 -> same row
    int ci = f / 9;
    int rem = f - ci * 9;
    int kr = rem / 3;
    int kc = rem - kr * 3;
    int h = oh * 2 + kr - 1;
    short8 outv;
    if (h >= 0 && h < 160) {
        const float* row = P3 + (size_t)(g * 48 + 32 + ci) * NPIX + h * 160;
#pragma unroll
        for (int e = 0; e < 8; e++) {
            int w = (ow0 + e) * 2 + kc - 1;
            float v = (w >= 0 && w < 160) ? row[w] : 0.f;
            outv[e] = (short)f2bf(v);
        }
    } else {
#pragma unroll
        for (int e = 0; e < 8; e++) outv[e] = 0;
    }
    *(short8*)(VT + ((size_t)g * 144 + f) * 6400 + l0) = outv;
}

// ---------------- K3: MFMA flash attention (S^T = K@Q^T) ----------------
// R3 version verbatim (measured 97us @ ns=5). 256 thr = 4 waves x 32 queries,
// keys in nsplit ranges of kps, tiles of 64. Async-staged: tile t+1
// global->reg issued before compute(t), reg->LDS after.
__global__ __launch_bounds__(256, 2) void k_attn(
    const unsigned short* __restrict__ PatQK, const unsigned short* __restrict__ VT,
    float* __restrict__ ml, unsigned short* __restrict__ Opart,
    int nsplit, int kps) {
    __shared__ unsigned short Ks[64 * 156];    // K tile, rows padded 144->156
    __shared__ unsigned short Vs[160 * 76];    // V^T tile, rows padded 64->76
    __shared__ unsigned short Pl[4 * 32 * 76]; // per-wave P^T as [q][k]

    int tid = threadIdx.x;
    int lane = tid & 63;
    int w = tid >> 6;
    int l31 = lane & 31;
    int h5 = lane >> 5;
    int split = blockIdx.y, g = blockIdx.z;
    int q = blockIdx.x * 128 + w * 32 + l31;
    int nIter = kps >> 6;

    const unsigned short* Qg = PatQK + ((size_t)g * 2 + 0) * 6400 * 144;
    const unsigned short* Kg = PatQK + ((size_t)g * 2 + 1) * 6400 * 144 + (size_t)split * kps * 144;
    const unsigned short* Vg = VT + (size_t)g * 144 * 6400 + split * kps;

    // Q fragments (B operand) pinned in registers: lane reads its query row
    short8 qf[9];
#pragma unroll
    for (int fs = 0; fs < 9; fs++)
        qf[fs] = *(const short8*)(Qg + (size_t)q * 144 + fs * 16 + h5 * 8);

    floatx16 O[5];
#pragma unroll
    for (int i = 0; i < 5; i++) O[i] = (floatx16)0.f;
    float m = -1e30f, lsum = 0.f;

    unsigned short* Plw = Pl + w * (32 * 76);

    short8 stg[9];
    // prologue: stage tile 0
    {
#pragma unroll
        for (int j = 0; j < 9; j++) {
            int c = tid + 256 * j;
            if (c < 1152) {
                int row = c / 18, col = c - row * 18;
                stg[j] = *(const short8*)(Kg + row * 144 + col * 8);
            } else {
                int vv = c - 1152;
                int f = vv >> 3, col = vv & 7;
                stg[j] = *(const short8*)(Vg + (size_t)f * 6400 + col * 8);
            }
        }
#pragma unroll
        for (int j = 0; j < 9; j++) {
            int c = tid + 256 * j;
            if (c < 1152) {
                int row = c / 18, col = c - row * 18;
                *(short8*)&Ks[row * 156 + col * 8] = stg[j];
            } else {
                int vv = c - 1152;
                int f = vv >> 3, col = vv & 7;
                *(short8*)&Vs[f * 76 + col * 8] = stg[j];
            }
        }
    }

    for (int it = 0; it < nIter; it++) {
        __syncthreads();  // staged tile `it` visible

        // issue next tile's global loads early; latency hides under compute
        if (it + 1 < nIter) {
            const unsigned short* Kt = Kg + (it + 1) * 64 * 144;
            const unsigned short* Vt = Vg + (it + 1) * 64;
#pragma unroll
            for (int j = 0; j < 9; j++) {
                int c = tid + 256 * j;
                if (c < 1152) {
                    int row = c / 18, col = c - row * 18;
                    stg[j] = *(const short8*)(Kt + row * 144 + col * 8);
                } else {
                    int vv = c - 1152;
                    int f = vv >> 3, col = vv & 7;
                    stg[j] = *(const short8*)(Vt + (size_t)f * 6400 + col * 8);
                }
            }
        }

        // S^T: two 32x32 C-tiles (keys 0-31 / 32-63), reduce over f=144 in 9 steps
        floatx16 S0 = (floatx16)0.f, S1 = (floatx16)0.f;
#pragma unroll
        for (int fs = 0; fs < 9; fs++) {
            short8 a0 = *(const short8*)&Ks[l31 * 156 + fs * 16 + h5 * 8];
            short8 a1 = *(const short8*)&Ks[(32 + l31) * 156 + fs * 16 + h5 * 8];
            S0 = __builtin_amdgcn_mfma_f32_32x32x16_bf16(a0, qf[fs], S0, 0, 0, 0);
            S1 = __builtin_amdgcn_mfma_f32_32x32x16_bf16(a1, qf[fs], S1, 0, 0, 0);
        }

        // online softmax: this lane's 32 scores all belong to query col=l31
        float mt = -1e30f;
#pragma unroll
        for (int r = 0; r < 16; r++) { mt = fmaxf(mt, S0[r]); mt = fmaxf(mt, S1[r]); }
        mt = fmaxf(mt, __shfl_xor(mt, 32, 64));
        // defer-max: keep stale m unless it grew > TAU (P bounded by 2^(14.43*TAU))
        bool upd = mt > m + TAU;
        float mnew = upd ? mt : m;
        float alpha = upd ? exp2f(LOG2E10 * (m - mnew)) : 1.f;
        float ps = 0.f;
#pragma unroll
        for (int r = 0; r < 16; r++) {  // exp in place: S reused as P
            S0[r] = exp2f(LOG2E10 * (S0[r] - mnew));
            S1[r] = exp2f(LOG2E10 * (S1[r] - mnew));
            ps += S0[r] + S1[r];
        }
        ps += __shfl_xor(ps, 32, 64);
        lsum = lsum * alpha + ps;
        m = mnew;
        if (__any(alpha < 1.f)) {
#pragma unroll
            for (int t5 = 0; t5 < 5; t5++)
#pragma unroll
                for (int r = 0; r < 16; r++) O[t5][r] *= alpha;
        }

        // P^T -> per-wave LDS as [q][k] bf16 (k = 8*rg + 4*h5 + rr, +32 tile1)
#pragma unroll
        for (int rg = 0; rg < 4; rg++) {
            ushort4 w0, w1;
            w0.x = f2bf(S0[4 * rg + 0]); w0.y = f2bf(S0[4 * rg + 1]);
            w0.z = f2bf(S0[4 * rg + 2]); w0.w = f2bf(S0[4 * rg + 3]);
            w1.x = f2bf(S1[4 * rg + 0]); w1.y = f2bf(S1[4 * rg + 1]);
            w1.z = f2bf(S1[4 * rg + 2]); w1.w = f2bf(S1[4 * rg + 3]);
            *(ushort4*)&Plw[l31 * 76 + rg * 8 + h5 * 4] = w0;
            *(ushort4*)&Plw[l31 * 76 + 32 + rg * 8 + h5 * 4] = w1;
        }

        // O^T += V^T @ P^T  (A from Vs, B from Plw)
#pragma unroll
        for (int ks = 0; ks < 4; ks++) {
            short8 pb = *(const short8*)&Plw[l31 * 76 + ks * 16 + h5 * 8];
#pragma unroll
            for (int ft = 0; ft < 5; ft++) {
                short8 va = *(const short8*)&Vs[(ft * 32 + l31) * 76 + ks * 16 + h5 * 8];
                O[ft] = __builtin_amdgcn_mfma_f32_32x32x16_bf16(va, pb, O[ft], 0, 0, 0);
            }
        }

        __syncthreads();  // all waves done reading tile `it`
        if (it + 1 < nIter) {
#pragma unroll
            for (int j = 0; j < 9; j++) {  // write staged regs (vmcnt waited here)
                int c = tid + 256 * j;
                if (c < 1152) {
                    int row = c / 18, col = c - row * 18;
                    *(short8*)&Ks[row * 156 + col * 8] = stg[j];
                } else {
                    int vv = c - 1152;
                    int f = vv >> 3, col = vv & 7;
                    *(short8*)&Vs[f * 76 + col * 8] = stg[j];
                }
            }
        }
    }

    if (h5 == 0)
        ((float2*)ml)[((size_t)g * nsplit + split) * 6400 + q] = make_float2(m, lsum);

    unsigned short* Og = Opart + (((size_t)g * nsplit + split) * 6400 + q) * 144;
#pragma unroll
    for (int ft = 0; ft < 5; ft++)
#pragma unroll
        for (int rg = 0; rg < 4; rg++) {
            int f = ft * 32 + rg * 8 + h5 * 4;
            if (f < 144) {
                ushort4 st;
                st.x = f2bf(O[ft][4 * rg + 0]); st.y = f2bf(O[ft][4 * rg + 1]);
                st.z = f2bf(O[ft][4 * rg + 2]); st.w = f2bf(O[ft][4 * rg + 3]);
                *(ushort4*)(Og + f) = st;
            }
        }
}

// ---------------- K3b: merge ksplit partials ----------------
__global__ void k_merge(const float* __restrict__ mlp, const unsigned short* __restrict__ Opart,
                        float* __restrict__ Zi, int nsplit) {
    int idx = blockIdx.x * 256 + threadIdx.x;  // 2*6400*36 exact
    int fg = idx % 36;
    int q = (idx / 36) % 6400;
    int g = idx / (36 * 6400);
    const float2* ml2 = (const float2*)mlp;
    float2 s[5];
    float ms = -1e30f;
#pragma unroll
    for (int k = 0; k < 5; k++) {
        s[k] = (k < nsplit) ? ml2[((size_t)g * nsplit + k) * 6400 + q]
                            : make_float2(-1e30f, 0.f);
        ms = fmaxf(ms, s[k].x);
    }
    float wgt[5], denom = 0.f;
#pragma unroll
    for (int k = 0; k < 5; k++) {
        wgt[k] = exp2f(LOG2E10 * (s[k].x - ms));
        denom += wgt[k] * s[k].y;
    }
    float inv = 1.f / denom;
    float a0 = 0.f, a1 = 0.f, a2 = 0.f, a3 = 0.f;
#pragma unroll
    for (int k = 0; k < 5; k++) {
        if (k < nsplit) {
            ushort4 u = *(const ushort4*)(Opart + (((size_t)g * nsplit + k) * 6400 + q) * 144 + fg * 4);
            a0 += wgt[k] * bf2f(u.x); a1 += wgt[k] * bf2f(u.y);
            a2 += wgt[k] * bf2f(u.z); a3 += wgt[k] * bf2f(u.w);
        }
    }
    float4 out = make_float4(a0 * inv, a1 * inv, a2 * inv, a3 * inv);
    *(float4*)(Zi + ((size_t)g * 6400 + q) * 144 + fg * 4) = out;
}

// ---------------- K4: fold (overlap-add) + mask normalization ----------------
__global__ void k_fold(const float* __restrict__ Zi, float* __restrict__ zi2) {
    int idx = blockIdx.x * 256 + threadIdx.x;  // 2*16*25600 exact
    int pix = idx % NPIX;
    int ci = (idx / NPIX) & 15;
    int g = idx / (16 * NPIX);
    int h = pix / 160, w = pix % 160;
    int ohs[2], krs[2], nh = 0;
#pragma unroll
    for (int kr = 0; kr < 3; kr++) {
        int t = h + 1 - kr;
        if (t >= 0 && (t & 1) == 0 && (t >> 1) < 80) { ohs[nh] = t >> 1; krs[nh] = kr; nh++; }
    }
    int ows[2], kcs[2], nw = 0;
#pragma unroll
    for (int kc = 0; kc < 3; kc++) {
        int t = w + 1 - kc;
        if (t >= 0 && (t & 1) == 0 && (t >> 1) < 80) { ows[nw] = t >> 1; kcs[nw] = kc; nw++; }
    }
    float sm = 0.f;
    for (int a = 0; a < nh; a++)
        for (int bb = 0; bb < nw; bb++) {
            int l = ohs[a] * 80 + ows[bb];
            int f = ci * 9 + krs[a] * 3 + kcs[bb];
            sm += Zi[((size_t)g * 6400 + l) * 144 + f];
        }
    zi2[idx] = sm / (float)(nh * nw);
}

// ---------------- K5: out = b + conv1x1(zi2 broadcast over D) ----------------
__global__ void k_final(const float* __restrict__ b, const float* __restrict__ zi2,
                        const float* __restrict__ Ww, const float* __restrict__ Wb,
                        float* __restrict__ out) {
    __shared__ float z[16 * 64];
    __shared__ float Wl[64 * 16];
    __shared__ float Bl[64];
    int tid = threadIdx.x;
    int g = blockIdx.y;
    int pxb = blockIdx.x * 64;
    for (int i = tid; i < 1024; i += 256) {
        int ci = i >> 6, px = i & 63;
        z[i] = zi2[(size_t)(g * 16 + ci) * NPIX + pxb + px];
        Wl[i] = Ww[i];
    }
    if (tid < 64) Bl[tid] = Wb[tid];
    __syncthreads();

    int px4 = tid & 15;
    int cg = tid >> 4;
    float acc[4][4];
#pragma unroll
    for (int c4 = 0; c4 < 4; c4++) {
        float bv = Bl[cg + 16 * c4];
#pragma unroll
        for (int j = 0; j < 4; j++) acc[c4][j] = bv;
    }
#pragma unroll
    for (int ci = 0; ci < 16; ci++) {
        float zv[4];
#pragma unroll
        for (int j = 0; j < 4; j++) zv[j] = z[ci * 64 + px4 * 4 + j];
#pragma unroll
        for (int c4 = 0; c4 < 4; c4++) {
            float wv = Wl[(cg + 16 * c4) * 16 + ci];
#pragma unroll
            for (int j = 0; j < 4; j++) acc[c4][j] += wv * zv[j];
        }
    }
    for (int d = 0; d < 8; d++) {
#pragma unroll
        for (int c4 = 0; c4 < 4; c4++) {
            int c = cg + 16 * c4;
            size_t base = ((size_t)(g * 64 + c) * 8 + d) * NPIX + pxb + px4 * 4;
            float4 bv = *(const float4*)(b + base);
            float4 ov = make_float4(bv.x + acc[c4][0], bv.y + acc[c4][1],
                                    bv.z + acc[c4][2], bv.w + acc[c4][3]);
            *(float4*)(out + base) = ov;
        }
    }
}

extern "C" void kernel_launch(void* const* d_in, const int* in_sizes, int n_in,
                              void* d_out, int out_size, void* d_ws, size_t ws_size,
                              hipStream_t stream) {
    const float* b   = (const float*)d_in[0];
    const float* gw  = (const float*)d_in[1];
    const float* gb  = (const float*)d_in[2];
    const float* thw = (const float*)d_in[3];
    const float* thb = (const float*)d_in[4];
    const float* phw = (const float*)d_in[5];
    const float* phb = (const float*)d_in[6];
    const float* Ww  = (const float*)d_in[7];
    const float* Wb  = (const float*)d_in[8];
    float* out = (float*)d_out;
    float* ws = (float*)d_ws;

    const size_t need5 = 30003200;  // bytes for ns=5 layout
    int ns = (ws_size >= need5) ? 5 : 4;
    int kps = 6400 / ns;

    unsigned short* PatQK = (unsigned short*)ws;                       // 3,686,400 bf16
    unsigned short* VT    = (unsigned short*)(ws + 1843200);           // 1,843,200 bf16
    float*          ml    = ws + 2764800;                              // 2*ns*6400*2 f32
    size_t off_P3 = 2764800 + (size_t)2 * ns * 6400 * 2;
    float*          P3    = ws + off_P3;                               // 2,457,600 f32
    unsigned short* Opart = (unsigned short*)(ws + off_P3);            // overlays P3
    float*          Zi    = ws;                                        // overlays PatQK
    float*          zi2   = ws + 1843200;                              // overlays VT

    k_proj<<<dim3(400, 2), 256, 0, stream>>>(b, gw, gb, thw, thb, phw, phb, P3);
    k_unfold_qk<<<dim3(1800), 256, 0, stream>>>(P3, PatQK);
    k_unfold_v<<<dim3(900), 256, 0, stream>>>(P3, VT);
    k_attn<<<dim3(50, ns, 2), 256, 0, stream>>>(PatQK, VT, ml, Opart, ns, kps);
    k_merge<<<dim3(1800), 256, 0, stream>>>(ml, Opart, Zi, ns);
    k_fold<<<dim3(3200), 256, 0, stream>>>(Zi, zi2);
    k_final<<<dim3(400, 2), 256, 0, stream>>>(b, zi2, Ww, Wb, out);
}